// Round 1
// baseline (1763.778 us; speedup 1.0000x reference)
//
#include <hip/hip_runtime.h>

// Elman RNN on MI355X. B=64, T=2048, D=H=256.
// Kernel 1: px = xs @ W_ih + b_hh  (f16 MFMA, fp32 out) written into ys region.
// Kernel 2: sequential scan, 4 blocks x 16 rows, W_hh resident in VGPRs,
//           h round-trips through XOR-swizzled LDS each step. ys overwritten
//           in place (px[b,t] read before h[b,t] written).

typedef _Float16 half8 __attribute__((ext_vector_type(8)));
typedef float floatx4 __attribute__((ext_vector_type(4)));
typedef float f32x4 __attribute__((ext_vector_type(4)));

constexpr int Bb = 64, Tt = 2048, Dd = 256, Hh = 256;

// LDS address for h[row][col], row in [0,16), col in [0,256), f16 elements.
// 16B blocks along col; XOR-swizzle block index with (row&7) so that
// (a) A-fragment ds_read_b128 (fixed col-block per lane, row=lane&15) and
// (b) epilogue 2B h-writes are both bank-conflict-free.
__device__ __forceinline__ int lds_addr(int row, int col) {
    return row * 512 + ((((col >> 3) ^ (row & 7)) & 31) << 4) + ((col & 7) << 1);
}

__device__ __forceinline__ float fast_tanh(float x) {
    // tanh(x) = 1 - 2/(exp2(x*2*log2(e)) + 1); exact at +/-inf, ~1e-6 abs err.
    float e = __builtin_amdgcn_exp2f(x * 2.885390081777927f);
    float r = __builtin_amdgcn_rcpf(e + 1.0f);
    return __builtin_fmaf(-2.0f, r, 1.0f);
}

// ---------------------------------------------------------------------------
// Kernel 1: px[b*T+t][n] = sum_k xs[b*T+t][k] * W_ih[k][n] + b_hh[n]
// Block: 256 thr (4 waves). Wave w owns cols [64w, 64w+64) (4 n-tiles),
// W_ih fragments register-resident (128 VGPRs). Block processes 8 row-tiles
// of 16; all 4 waves read the same 16 xs rows (L1 absorbs the reuse).
// ---------------------------------------------------------------------------
__global__ __launch_bounds__(256, 2) void px_gemm(const float* __restrict__ xs,
                                                  const float* __restrict__ Wih,
                                                  const float* __restrict__ bhh,
                                                  float* __restrict__ px) {
    const int lane = threadIdx.x & 63;
    const int w = threadIdx.x >> 6;   // 0..3
    const int q = lane >> 4;          // 0..3
    const int m = lane & 15;

    // B fragments: B[k][n], n = lane&15 + tile base, k = 8*q + j + 32*c.
    half8 bf[4][8];
#pragma unroll
    for (int tt = 0; tt < 4; ++tt) {
        const int n = 64 * w + 16 * tt + m;
#pragma unroll
        for (int c = 0; c < 8; ++c) {
            half8 f;
#pragma unroll
            for (int j = 0; j < 8; ++j)
                f[j] = (_Float16)Wih[(32 * c + 8 * q + j) * Hh + n];
            bf[tt][c] = f;
        }
    }
    float bias[4];
#pragma unroll
    for (int tt = 0; tt < 4; ++tt) bias[tt] = bhh[64 * w + 16 * tt + m];

    for (int i = 0; i < 8; ++i) {
        const int tau = blockIdx.x * 8 + i;             // 16-row tile index
        const float* arow = xs + (size_t)(tau * 16 + m) * Dd;
        half8 af[8];
#pragma unroll
        for (int c = 0; c < 8; ++c) {
            f32x4 lo = *(const f32x4*)(arow + 32 * c + 8 * q);
            f32x4 hi = *(const f32x4*)(arow + 32 * c + 8 * q + 4);
            half8 f;
            f[0] = (_Float16)lo[0]; f[1] = (_Float16)lo[1];
            f[2] = (_Float16)lo[2]; f[3] = (_Float16)lo[3];
            f[4] = (_Float16)hi[0]; f[5] = (_Float16)hi[1];
            f[6] = (_Float16)hi[2]; f[7] = (_Float16)hi[3];
            af[c] = f;
        }
        floatx4 acc[4];
#pragma unroll
        for (int tt = 0; tt < 4; ++tt) {
            acc[tt][0] = bias[tt]; acc[tt][1] = bias[tt];
            acc[tt][2] = bias[tt]; acc[tt][3] = bias[tt];
        }
#pragma unroll
        for (int c = 0; c < 8; ++c)
#pragma unroll
            for (int tt = 0; tt < 4; ++tt)
                acc[tt] = __builtin_amdgcn_mfma_f32_16x16x32_f16(af[c], bf[tt][c], acc[tt], 0, 0, 0);
        // C layout: row = 4*q + r, col = 16*tile + (lane&15)
#pragma unroll
        for (int tt = 0; tt < 4; ++tt)
#pragma unroll
            for (int r = 0; r < 4; ++r)
                px[(size_t)(tau * 16 + 4 * q + r) * Hh + 64 * w + 16 * tt + m] = acc[tt][r];
    }
}

// ---------------------------------------------------------------------------
// Kernel 2: scan. Grid = 4 blocks (16 batch rows each), 512 thr = 8 waves.
// Wave w owns cols [32w, 32w+32) (2 n-tiles). W_hh fragments in 64 VGPRs.
// Per step: prefetch px[t+1] (regs, double-buffered), read A frags from LDS,
// 16 MFMA, tanh, store ys (over px) + write h to ping-pong LDS. 1 barrier/step.
// ---------------------------------------------------------------------------
__global__ __launch_bounds__(512, 1) void rnn_scan(const float* __restrict__ c0,
                                                   const float* __restrict__ Whh,
                                                   float* __restrict__ hfin,
                                                   float* __restrict__ ys) {
    __shared__ alignas(16) unsigned char hb[2][8192];
    const int g = blockIdx.x;         // row group: rows [16g, 16g+16)
    const int lane = threadIdx.x & 63;
    const int w = threadIdx.x >> 6;   // 0..7
    const int q = lane >> 4;
    const int m = lane & 15;

    // W_hh B fragments (one-time, scattered fp32 loads + cvt).
    half8 bf[2][8];
#pragma unroll
    for (int tt = 0; tt < 2; ++tt) {
        const int n = 32 * w + 16 * tt + m;
#pragma unroll
        for (int c = 0; c < 8; ++c) {
            half8 f;
#pragma unroll
            for (int j = 0; j < 8; ++j)
                f[j] = (_Float16)Whh[(32 * c + 8 * q + j) * Hh + n];
            bf[tt][c] = f;
        }
    }

    // h_0 = c rows -> LDS buffer 0 (f16, swizzled).
    for (int i = threadIdx.x; i < 16 * 256; i += 512) {
        const int row = i >> 8, col = i & 255;
        *(_Float16*)&hb[0][lds_addr(row, col)] = (_Float16)c0[(16 * g + row) * Hh + col];
    }

    size_t rowoff[4];
#pragma unroll
    for (int r = 0; r < 4; ++r)
        rowoff[r] = (size_t)(16 * g + 4 * q + r) * Tt * Hh;
    int coloff[2];
    coloff[0] = 32 * w + m;
    coloff[1] = 32 * w + 16 + m;

    // Prime px for t=0.
    float pxc[8], pxn[8];
#pragma unroll
    for (int tt = 0; tt < 2; ++tt)
#pragma unroll
        for (int r = 0; r < 4; ++r)
            pxc[4 * tt + r] = ys[rowoff[r] + coloff[tt]];

    __syncthreads();

    for (int t = 0; t < Tt; ++t) {
        const int p = t & 1;
        const int tn = (t + 1 < Tt) ? t + 1 : t;  // last-iter value unused
        // Prefetch next step's px (in flight across the whole step).
#pragma unroll
        for (int tt = 0; tt < 2; ++tt)
#pragma unroll
            for (int r = 0; r < 4; ++r)
                pxn[4 * tt + r] = ys[rowoff[r] + (size_t)tn * Hh + coloff[tt]];

        // A fragments: A[m=lane&15][k=8q+j+32c] -> 8x ds_read_b128, swizzled.
        half8 af[8];
#pragma unroll
        for (int c = 0; c < 8; ++c)
            af[c] = *(const half8*)&hb[p][m * 512 + ((((4 * c + q) ^ (m & 7)) & 31) << 4)];

        floatx4 acc[2];
#pragma unroll
        for (int tt = 0; tt < 2; ++tt) {
            acc[tt][0] = pxc[4 * tt + 0]; acc[tt][1] = pxc[4 * tt + 1];
            acc[tt][2] = pxc[4 * tt + 2]; acc[tt][3] = pxc[4 * tt + 3];
        }
        // Tile-major so tile-0 epilogue can overlap tile-1 MFMA chain.
#pragma unroll
        for (int tt = 0; tt < 2; ++tt)
#pragma unroll
            for (int c = 0; c < 8; ++c)
                acc[tt] = __builtin_amdgcn_mfma_f32_16x16x32_f16(af[c], bf[tt][c], acc[tt], 0, 0, 0);

#pragma unroll
        for (int tt = 0; tt < 2; ++tt) {
#pragma unroll
            for (int r = 0; r < 4; ++r) {
                const float h = fast_tanh(acc[tt][r]);
                const int row = 4 * q + r;
                const int col = coloff[tt];
                ys[rowoff[r] + (size_t)t * Hh + col] = h;          // overwrite px in place
                *(_Float16*)&hb[p ^ 1][lds_addr(row, col)] = (_Float16)h;
                if (t == Tt - 1) hfin[(16 * g + row) * Hh + col] = h;
            }
        }
#pragma unroll
        for (int k = 0; k < 8; ++k) pxc[k] = pxn[k];
        __syncthreads();
    }
}

extern "C" void kernel_launch(void* const* d_in, const int* in_sizes, int n_in,
                              void* d_out, int out_size, void* d_ws, size_t ws_size,
                              hipStream_t stream) {
    const float* c0  = (const float*)d_in[0];  // [B,H]
    const float* xs  = (const float*)d_in[1];  // [B,T,D]
    const float* Wih = (const float*)d_in[2];  // [D,H]
    const float* Whh = (const float*)d_in[3];  // [H,H]
    const float* bhh = (const float*)d_in[4];  // [H]
    float* out = (float*)d_out;
    float* hfin = out;                 // [B,H]
    float* ys = out + Bb * Hh;         // [B,T,H] — also holds px between kernels

    // 1024 blocks * 8 tiles * 16 rows = 131072 = B*T rows.
    px_gemm<<<1024, 256, 0, stream>>>(xs, Wih, bhh, ys);
    // 4 blocks * 16 rows = 64 batch chains.
    rnn_scan<<<Bb / 16, 512, 0, stream>>>(c0, Whh, hfin, ys);
}